// Round 10
// baseline (260.772 us; speedup 1.0000x reference)
//
#include <hip/hip_runtime.h>
#include <math.h>

#define N_NODES 50000
#define N_EDGES 800000
#define IN_DIM 128
#define HID 512
#define OUT_DIM 40
#define NB_SCAN ((N_NODES + 255) / 256)   // 196
#define NRANGE 8
#define RANGE_SZ ((N_NODES + NRANGE - 1) / NRANGE)   // 6250
#define NCHUNK 250
#define PER_CHUNK 3200   // NCHUNK*PER_CHUNK == N_EDGES, %4 == 0
#define FB_ROWS 32
#define NB_FUSED ((N_NODES + FB_ROWS - 1) / FB_ROWS)   // 1563

typedef __attribute__((ext_vector_type(8))) short bf16x8;
typedef __attribute__((ext_vector_type(4))) float f32x4;

__device__ __forceinline__ ushort f2bf(float f) {
    unsigned u = __float_as_uint(f);
    u += 0x7fff + ((u >> 16) & 1);   // round-to-nearest-even
    return (ushort)(u >> 16);
}

__device__ __forceinline__ float bf2f(ushort u) {
    return __uint_as_float(((unsigned)u) << 16);
}

__device__ __forceinline__ unsigned pack2bf(float lo, float hi) {
    return ((unsigned)f2bf(hi) << 16) | (unsigned)f2bf(lo);
}

// async global->LDS, 16B per lane, dest = wave-uniform base + lane*16
__device__ __forceinline__ void gload_lds16(const ushort* g, ushort* l) {
    __builtin_amdgcn_global_load_lds(
        (__attribute__((address_space(1))) void*)g,
        (__attribute__((address_space(3))) void*)l, 16, 0, 0);
}

__global__ void zero_ints(int* __restrict__ a, int n) {
    int i = blockIdx.x * blockDim.x + threadIdx.x;
    if (i < n) a[i] = 0;
}

// XCD-range-partitioned histogram, 2000 blocks (8 ranges x 250 chunks)
__global__ void count_deg_part(const int* __restrict__ dst, int* __restrict__ deg) {
    int range = blockIdx.x & (NRANGE - 1);
    int chunk = blockIdx.x >> 3;
    int lo = range * RANGE_SZ;
    int hi = lo + RANGE_SZ; if (hi > N_NODES) hi = N_NODES;
    int beg = chunk * PER_CHUNK;
    for (int e = beg + threadIdx.x * 4; e < beg + PER_CHUNK; e += 1024) {
        int4 d4 = *(const int4*)(dst + e);
        if (d4.x >= lo && d4.x < hi) atomicAdd(&deg[d4.x], 1);
        if (d4.y >= lo && d4.y < hi) atomicAdd(&deg[d4.y], 1);
        if (d4.z >= lo && d4.z < hi) atomicAdd(&deg[d4.z], 1);
        if (d4.w >= lo && d4.w < hi) atomicAdd(&deg[d4.w], 1);
    }
}

// --- 3-stage parallel exclusive scan: deg[50000] -> row_ptr[50001] ---
__global__ void deg_block_sums(const int* __restrict__ deg, int* __restrict__ bsum) {
    __shared__ int red[256];
    int tid = threadIdx.x;
    int i = blockIdx.x * 256 + tid;
    red[tid] = (i < N_NODES) ? deg[i] : 0;
    __syncthreads();
    #pragma unroll
    for (int off = 128; off; off >>= 1) {
        if (tid < off) red[tid] += red[tid + off];
        __syncthreads();
    }
    if (tid == 0) bsum[blockIdx.x] = red[0];
}

__global__ void scan_bsum(int* __restrict__ bsum) {
    __shared__ int s[256];
    int tid = threadIdx.x;
    int v = (tid < NB_SCAN) ? bsum[tid] : 0;
    s[tid] = v;
    __syncthreads();
    #pragma unroll
    for (int off = 1; off < 256; off <<= 1) {
        int add = (tid >= off) ? s[tid - off] : 0;
        __syncthreads();
        s[tid] += add;
        __syncthreads();
    }
    if (tid < NB_SCAN) bsum[tid] = s[tid] - v;   // exclusive
}

__global__ void scan_fill(const int* __restrict__ deg, const int* __restrict__ bsum,
                          int* __restrict__ row_ptr) {
    __shared__ int s[256];
    int tid = threadIdx.x;
    int i = blockIdx.x * 256 + tid;
    int v = (i < N_NODES) ? deg[i] : 0;
    s[tid] = v;
    __syncthreads();
    #pragma unroll
    for (int off = 1; off < 256; off <<= 1) {
        int add = (tid >= off) ? s[tid - off] : 0;
        __syncthreads();
        s[tid] += add;
        __syncthreads();
    }
    int excl = s[tid] - v + bsum[blockIdx.x];
    if (i < N_NODES) row_ptr[i] = excl;
    if (i == N_NODES - 1) row_ptr[N_NODES] = excl + v;
}

// XCD-range-partitioned CSR fill, 2000 blocks, int4 loads of src+dst
__global__ void fill_csr_part(const int* __restrict__ src, const int* __restrict__ dst,
                              const int* __restrict__ row_ptr, int* __restrict__ cursor,
                              int* __restrict__ csr_src) {
    int range = blockIdx.x & (NRANGE - 1);
    int chunk = blockIdx.x >> 3;
    int lo = range * RANGE_SZ;
    int hi = lo + RANGE_SZ; if (hi > N_NODES) hi = N_NODES;
    int beg = chunk * PER_CHUNK;
    for (int e = beg + threadIdx.x * 4; e < beg + PER_CHUNK; e += 1024) {
        int4 d4 = *(const int4*)(dst + e);
        int4 s4 = *(const int4*)(src + e);
        if (d4.x >= lo && d4.x < hi) {
            int pos = atomicAdd(&cursor[d4.x], 1);
            csr_src[row_ptr[d4.x] + pos] = s4.x;
        }
        if (d4.y >= lo && d4.y < hi) {
            int pos = atomicAdd(&cursor[d4.y], 1);
            csr_src[row_ptr[d4.y] + pos] = s4.y;
        }
        if (d4.z >= lo && d4.z < hi) {
            int pos = atomicAdd(&cursor[d4.z], 1);
            csr_src[row_ptr[d4.z] + pos] = s4.z;
        }
        if (d4.w >= lo && d4.w < hi) {
            int pos = atomicAdd(&cursor[d4.w], 1);
            csr_src[row_ptr[d4.w] + pos] = s4.w;
        }
    }
}

// abuf[n][128..255] = bf16(x[n][:])  (must run BEFORE agg_x)
__global__ void cvt_x(const float* __restrict__ x, ushort* __restrict__ abuf) {
    int i = blockIdx.x * blockDim.x + threadIdx.x;
    if (i >= N_NODES * 32) return;
    int n = i >> 5, q = i & 31;
    float4 v = *(const float4*)(x + (size_t)n * 128 + q * 4);
    ushort4 o;
    o.x = f2bf(v.x); o.y = f2bf(v.y); o.z = f2bf(v.z); o.w = f2bf(v.w);
    *(ushort4*)(abuf + (size_t)n * 256 + 128 + q * 4) = o;
}

// one wave per node: mean of bf16-x[src] rows (from abuf x-half, 256B/row)
__global__ void agg_x(const int* __restrict__ row_ptr,
                      const int* __restrict__ csr_src, ushort* __restrict__ abuf) {
    int wid = threadIdx.x >> 6;
    int lane = threadIdx.x & 63;
    int n = blockIdx.x * 4 + wid;
    if (n >= N_NODES) return;
    int beg = row_ptr[n], end = row_ptr[n + 1];
    int half = lane >> 5, l32 = lane & 31;
    const ushort* xb = abuf + 128;   // x-half of each 256-elem row
    float a0 = 0, a1 = 0, a2 = 0, a3 = 0;
    float b0 = 0, b1 = 0, b2_ = 0, b3 = 0;
    int e = beg + half;
    for (; e + 2 < end; e += 4) {
        int s0 = csr_src[e], s1 = csr_src[e + 2];
        ushort4 v0 = *(const ushort4*)(xb + (size_t)s0 * 256 + l32 * 4);
        ushort4 v1 = *(const ushort4*)(xb + (size_t)s1 * 256 + l32 * 4);
        a0 += bf2f(v0.x); a1 += bf2f(v0.y); a2 += bf2f(v0.z); a3 += bf2f(v0.w);
        b0 += bf2f(v1.x); b1 += bf2f(v1.y); b2_ += bf2f(v1.z); b3 += bf2f(v1.w);
    }
    if (e < end) {
        int s = csr_src[e];
        ushort4 v = *(const ushort4*)(xb + (size_t)s * 256 + l32 * 4);
        a0 += bf2f(v.x); a1 += bf2f(v.y); a2 += bf2f(v.z); a3 += bf2f(v.w);
    }
    a0 += b0; a1 += b1; a2 += b2_; a3 += b3;
    a0 += __shfl_xor(a0, 32);
    a1 += __shfl_xor(a1, 32);
    a2 += __shfl_xor(a2, 32);
    a3 += __shfl_xor(a3, 32);
    int d = end - beg; if (d < 1) d = 1;
    float inv = 1.0f / (float)d;
    if (half == 0) {
        ushort4 o;
        o.x = f2bf(a0 * inv); o.y = f2bf(a1 * inv);
        o.z = f2bf(a2 * inv); o.w = f2bf(a3 * inv);
        *(ushort4*)(abuf + (size_t)n * 256 + l32 * 4) = o;
    }
}

// merged weight transpose+convert: wt[512][256] and wt2[80][512]
__global__ void cvt_weights(const float* __restrict__ w1l, const float* __restrict__ w1r,
                            const float* __restrict__ w2l, const float* __restrict__ w2r,
                            ushort* __restrict__ wt, ushort* __restrict__ wt2) {
    int i = blockIdx.x * blockDim.x + threadIdx.x;
    if (i < 512 * 256) {
        int k = i >> 9, c = i & 511;
        float v = (k < 128) ? w1l[(size_t)k * 512 + c] : w1r[(size_t)(k - 128) * 512 + c];
        wt[(size_t)c * 256 + k] = f2bf(v);
    } else if (i < 512 * 256 + 80 * 512) {
        int j = i - 512 * 256;
        int c = j >> 9, k = j & 511;
        float v = (c < 40) ? w2l[(size_t)k * 40 + c] : w2r[(size_t)k * 40 + (c - 40)];
        wt2[(size_t)c * 512 + k] = f2bf(v);
    }
}

// Fused layer1+layer2: per block, 32 rows x full 512 h-cols, h never hits HBM.
// Phase 1: h^T frags via swapped mfma(wt, Arow) -> lane&15 = h-row.
// Phase 2: shuffle-redistribute h-cols into B-frag k-slots, mfma(wt2, h).
// Cross-wave (k-split) partials reduced in LDS.
__global__ __launch_bounds__(256) void gemm_fused(
    const ushort* __restrict__ A,      // abuf [N][256]
    const ushort* __restrict__ WT,     // wt  [512][256]
    const ushort* __restrict__ WT2,    // wt2 [80][512]
    const float* __restrict__ bias,    // b1[512]
    ushort* __restrict__ p, float* __restrict__ r) {
    __shared__ ushort As[2][FB_ROWS * 64];      // 2 x 4KB
    __shared__ float part[4][FB_ROWS][80];      // 40KB
    int tid = threadIdx.x;
    int wave = tid >> 6, lane = tid & 63;
    int q = lane >> 4, r16 = lane & 15;
    int row0 = blockIdx.x * FB_ROWS;
    int colw = wave * 128;                      // wave's h-col range

    f32x4 acc1[8][2] = {};                      // [mf][rf]

    // ---- phase 1: K=256, BK=64, A dbuf-staged, wt direct from L2 ----
    {
        // prologue stage
        int o = wave * 1024 + lane * 16;
        int row = o >> 7;
        int s = (o >> 4) & 7;
        int ssrc = s ^ (row & 7);
        int gr = row0 + row; if (gr > N_NODES - 1) gr = N_NODES - 1;
        gload_lds16(A + (size_t)gr * 256 + (ssrc << 3), As[0] + wave * 512);
    }
    __syncthreads();
    #pragma unroll
    for (int t = 0; t < 4; ++t) {
        int cur = t & 1;
        if (t < 3) {
            int o = wave * 1024 + lane * 16;
            int row = o >> 7;
            int s = (o >> 4) & 7;
            int ssrc = s ^ (row & 7);
            int gr = row0 + row; if (gr > N_NODES - 1) gr = N_NODES - 1;
            gload_lds16(A + (size_t)gr * 256 + (t + 1) * 64 + (ssrc << 3),
                        As[cur ^ 1] + wave * 512);
        }
        int kk = t * 64;
        #pragma unroll
        for (int kc = 0; kc < 2; ++kc) {
            bf16x8 bf1[2];
            #pragma unroll
            for (int rf = 0; rf < 2; ++rf) {
                int row = rf * 16 + r16;
                int sbase = kc * 4 + q;
                bf1[rf] = *(const bf16x8*)(As[cur] + row * 64 + ((sbase ^ (row & 7)) << 3));
            }
            #pragma unroll
            for (int mf = 0; mf < 8; ++mf) {
                bf16x8 af1 = *(const bf16x8*)(WT + (size_t)(colw + mf * 16 + r16) * 256
                                              + kk + kc * 32 + q * 8);
                acc1[mf][0] = __builtin_amdgcn_mfma_f32_16x16x32_bf16(af1, bf1[0], acc1[mf][0], 0, 0, 0);
                acc1[mf][1] = __builtin_amdgcn_mfma_f32_16x16x32_bf16(af1, bf1[1], acc1[mf][1], 0, 0, 0);
            }
        }
        __syncthreads();
    }

    // bias + relu + pack to bf16 pairs
    // lane holds h[row0 + rf*16 + r16][colw + mf*16 + q*4 + j], j=0..3
    unsigned hp[8][2][2];   // [mf][rf][dw]: dw0=(j0,j1) dw1=(j2,j3)
    #pragma unroll
    for (int mf = 0; mf < 8; ++mf) {
        float4 b4 = *(const float4*)(bias + colw + mf * 16 + q * 4);
        #pragma unroll
        for (int rf = 0; rf < 2; ++rf) {
            float v0 = fmaxf(acc1[mf][rf][0] + b4.x, 0.f);
            float v1 = fmaxf(acc1[mf][rf][1] + b4.y, 0.f);
            float v2 = fmaxf(acc1[mf][rf][2] + b4.z, 0.f);
            float v3 = fmaxf(acc1[mf][rf][3] + b4.w, 0.f);
            hp[mf][rf][0] = pack2bf(v0, v1);
            hp[mf][rf][1] = pack2bf(v2, v3);
        }
    }

    // ---- phase 2: contract wave's 128 h-cols against wt2 ----
    f32x4 acc2[5][2] = {};                      // [ocf][rf]
    #pragma unroll
    for (int w32 = 0; w32 < 4; ++w32) {
        // wt2 A-frags for this k-window (shared across rf)
        bf16x8 af2[5];
        #pragma unroll
        for (int ocf = 0; ocf < 5; ++ocf)
            af2[ocf] = *(const bf16x8*)(WT2 + (size_t)(ocf * 16 + r16) * 512
                                        + colw + w32 * 32 + q * 8);
        int s0 = ((q & 1) * 2) * 16 + r16;      // src lane for i=0..3
        int s1 = s0 + 16;                       // src lane for i=4..7
        bool hiSel = (q >= 2);
        #pragma unroll
        for (int rf = 0; rf < 2; ++rf) {
            unsigned X0 = __shfl(hp[w32 * 2][rf][0], s0);
            unsigned Y0 = __shfl(hp[w32 * 2 + 1][rf][0], s0);
            unsigned X1 = __shfl(hp[w32 * 2][rf][1], s0);
            unsigned Y1 = __shfl(hp[w32 * 2 + 1][rf][1], s0);
            unsigned X2 = __shfl(hp[w32 * 2][rf][0], s1);
            unsigned Y2 = __shfl(hp[w32 * 2 + 1][rf][0], s1);
            unsigned X3 = __shfl(hp[w32 * 2][rf][1], s1);
            unsigned Y3 = __shfl(hp[w32 * 2 + 1][rf][1], s1);
            union { unsigned u[4]; bf16x8 v; } b2;
            b2.u[0] = hiSel ? Y0 : X0;
            b2.u[1] = hiSel ? Y1 : X1;
            b2.u[2] = hiSel ? Y2 : X2;
            b2.u[3] = hiSel ? Y3 : X3;
            #pragma unroll
            for (int ocf = 0; ocf < 5; ++ocf)
                acc2[ocf][rf] = __builtin_amdgcn_mfma_f32_16x16x32_bf16(af2[ocf], b2.v, acc2[ocf][rf], 0, 0, 0);
        }
    }

    // write per-wave partials: lane holds pp[row=rf*16+r16][oc=ocf*16+q*4+j]
    #pragma unroll
    for (int ocf = 0; ocf < 5; ++ocf)
        #pragma unroll
        for (int rf = 0; rf < 2; ++rf)
            *(f32x4*)&part[wave][rf * 16 + r16][ocf * 16 + q * 4] = acc2[ocf][rf];
    __syncthreads();

    // reduce 4 wave-partials and store
    int row = tid >> 3;                  // 0..31
    int oc0 = (tid & 7) * 10;            // 0,10..70
    int grow = row0 + row;
    if (grow < N_NODES) {
        #pragma unroll
        for (int k = 0; k < 10; ++k) {
            int oc = oc0 + k;
            float s = part[0][row][oc] + part[1][row][oc]
                    + part[2][row][oc] + part[3][row][oc];
            if (oc < 40) p[(size_t)grow * 40 + oc] = f2bf(s);
            else         r[(size_t)grow * 40 + (oc - 40)] = s;
        }
    }
}

// out = log_softmax(mean_j p[src] + b2 + r)  one wave per node, lanes 0..39
__global__ void final_kernel(const ushort* __restrict__ p, const float* __restrict__ rr,
                             const float* __restrict__ b2,
                             const int* __restrict__ row_ptr, const int* __restrict__ csr_src,
                             float* __restrict__ out) {
    int wid = threadIdx.x >> 6;
    int lane = threadIdx.x & 63;
    int n = blockIdx.x * 4 + wid;
    if (n >= N_NODES) return;
    int beg = row_ptr[n], end = row_ptr[n + 1];
    float acc0 = 0.f, acc1 = 0.f, acc2 = 0.f, acc3 = 0.f;
    int e = beg;
    if (lane < OUT_DIM) {
        for (; e + 3 < end; e += 4) {
            int s0 = csr_src[e], s1 = csr_src[e + 1];
            int s2 = csr_src[e + 2], s3 = csr_src[e + 3];
            acc0 += bf2f(p[(size_t)s0 * OUT_DIM + lane]);
            acc1 += bf2f(p[(size_t)s1 * OUT_DIM + lane]);
            acc2 += bf2f(p[(size_t)s2 * OUT_DIM + lane]);
            acc3 += bf2f(p[(size_t)s3 * OUT_DIM + lane]);
        }
        for (; e < end; ++e)
            acc0 += bf2f(p[(size_t)csr_src[e] * OUT_DIM + lane]);
    }
    int d = end - beg; if (d < 1) d = 1;
    float inv = 1.0f / (float)d;
    float v = (lane < OUT_DIM)
                  ? ((acc0 + acc1 + acc2 + acc3) * inv + b2[lane] + rr[(size_t)n * OUT_DIM + lane])
                  : -INFINITY;
    float m = v;
    #pragma unroll
    for (int off = 32; off; off >>= 1) m = fmaxf(m, __shfl_xor(m, off));
    float ex = (lane < OUT_DIM) ? expf(v - m) : 0.f;
    float ssum = ex;
    #pragma unroll
    for (int off = 32; off; off >>= 1) ssum += __shfl_xor(ssum, off);
    if (lane < OUT_DIM) out[(size_t)n * OUT_DIM + lane] = (v - m) - logf(ssum);
}

extern "C" void kernel_launch(void* const* d_in, const int* in_sizes, int n_in,
                              void* d_out, int out_size, void* d_ws, size_t ws_size,
                              hipStream_t stream) {
    const float* x    = (const float*)d_in[0];
    const int*   edge = (const int*)d_in[1];
    const int*   srce = edge;
    const int*   dste = edge + N_EDGES;
    const float* w1l  = (const float*)d_in[2];
    const float* b1   = (const float*)d_in[3];
    const float* w1r  = (const float*)d_in[4];
    const float* w2l  = (const float*)d_in[5];
    const float* b2   = (const float*)d_in[6];
    const float* w2r  = (const float*)d_in[7];
    float* out = (float*)d_out;

    char* ws = (char*)d_ws;
    size_t off = 0;
    auto alloc = [&](size_t bytes) -> void* {
        void* ptr = ws + off;
        off = (off + bytes + 255) & ~(size_t)255;
        return ptr;
    };
    int* deg     = (int*)alloc((size_t)2 * N_NODES * 4);
    int* cursor  = deg + N_NODES;
    int* row_ptr = (int*)alloc((size_t)(N_NODES + 1) * 4);
    int* bsum    = (int*)alloc((size_t)NB_SCAN * 4);
    int* csr_src = (int*)alloc((size_t)N_EDGES * 4);
    ushort* abuf = (ushort*)alloc((size_t)N_NODES * 256 * 2);   // [agg|x] bf16
    ushort* wt   = (ushort*)alloc((size_t)512 * 256 * 2);       // [w1_l;w1_r]^T bf16
    ushort* wt2  = (ushort*)alloc((size_t)80 * 512 * 2);        // [w2_l|w2_r]^T bf16
    ushort* p    = (ushort*)alloc((size_t)N_NODES * OUT_DIM * 2);  // p bf16
    float* rbuf  = (float*)alloc((size_t)N_NODES * OUT_DIM * 4);

    zero_ints<<<(2 * N_NODES + 255) / 256, 256, 0, stream>>>(deg, 2 * N_NODES);
    count_deg_part<<<NRANGE * NCHUNK, 256, 0, stream>>>(dste, deg);
    deg_block_sums<<<NB_SCAN, 256, 0, stream>>>(deg, bsum);
    scan_bsum<<<1, 256, 0, stream>>>(bsum);
    scan_fill<<<NB_SCAN, 256, 0, stream>>>(deg, bsum, row_ptr);
    fill_csr_part<<<NRANGE * NCHUNK, 256, 0, stream>>>(srce, dste, row_ptr, cursor, csr_src);
    cvt_x<<<(N_NODES * 32 + 255) / 256, 256, 0, stream>>>(x, abuf);
    cvt_weights<<<(512 * 256 + 80 * 512 + 255) / 256, 256, 0, stream>>>(w1l, w1r, w2l, w2r, wt, wt2);
    agg_x<<<(N_NODES + 3) / 4, 256, 0, stream>>>(row_ptr, csr_src, abuf);
    gemm_fused<<<NB_FUSED, 256, 0, stream>>>(abuf, wt, wt2, b1, p, rbuf);
    final_kernel<<<(N_NODES + 3) / 4, 256, 0, stream>>>(p, rbuf, b2, row_ptr, csr_src, out);
}

// Round 11
// 211.160 us; speedup vs baseline: 1.2349x; 1.2349x over previous
//
#include <hip/hip_runtime.h>
#include <math.h>

#define N_NODES 50000
#define N_EDGES 800000
#define IN_DIM 128
#define HID 512
#define OUT_DIM 40
#define NB_SCAN ((N_NODES + 255) / 256)   // 196
#define NRANGE 8
#define RANGE_SZ ((N_NODES + NRANGE - 1) / NRANGE)   // 6250
#define NCHUNK 250
#define PER_CHUNK 3200   // NCHUNK*PER_CHUNK == N_EDGES, %4 == 0

typedef __attribute__((ext_vector_type(8))) short bf16x8;
typedef __attribute__((ext_vector_type(4))) float f32x4;

__device__ __forceinline__ ushort f2bf(float f) {
    unsigned u = __float_as_uint(f);
    u += 0x7fff + ((u >> 16) & 1);   // round-to-nearest-even
    return (ushort)(u >> 16);
}

__device__ __forceinline__ float bf2f(ushort u) {
    return __uint_as_float(((unsigned)u) << 16);
}

// async global->LDS, 16B per lane, dest = wave-uniform base + lane*16
__device__ __forceinline__ void gload_lds16(const ushort* g, ushort* l) {
    __builtin_amdgcn_global_load_lds(
        (__attribute__((address_space(1))) void*)g,
        (__attribute__((address_space(3))) void*)l, 16, 0, 0);
}

__global__ void zero_ints(int* __restrict__ a, int n) {
    int i = blockIdx.x * blockDim.x + threadIdx.x;
    if (i < n) a[i] = 0;
}

// XCD-range-partitioned histogram, 2000 blocks (8 ranges x 250 chunks)
__global__ void count_deg_part(const int* __restrict__ dst, int* __restrict__ deg) {
    int range = blockIdx.x & (NRANGE - 1);
    int chunk = blockIdx.x >> 3;
    int lo = range * RANGE_SZ;
    int hi = lo + RANGE_SZ; if (hi > N_NODES) hi = N_NODES;
    int beg = chunk * PER_CHUNK;
    for (int e = beg + threadIdx.x * 4; e < beg + PER_CHUNK; e += 1024) {
        int4 d4 = *(const int4*)(dst + e);
        if (d4.x >= lo && d4.x < hi) atomicAdd(&deg[d4.x], 1);
        if (d4.y >= lo && d4.y < hi) atomicAdd(&deg[d4.y], 1);
        if (d4.z >= lo && d4.z < hi) atomicAdd(&deg[d4.z], 1);
        if (d4.w >= lo && d4.w < hi) atomicAdd(&deg[d4.w], 1);
    }
}

// --- 3-stage parallel exclusive scan: deg[50000] -> row_ptr[50001] ---
__global__ void deg_block_sums(const int* __restrict__ deg, int* __restrict__ bsum) {
    __shared__ int red[256];
    int tid = threadIdx.x;
    int i = blockIdx.x * 256 + tid;
    red[tid] = (i < N_NODES) ? deg[i] : 0;
    __syncthreads();
    #pragma unroll
    for (int off = 128; off; off >>= 1) {
        if (tid < off) red[tid] += red[tid + off];
        __syncthreads();
    }
    if (tid == 0) bsum[blockIdx.x] = red[0];
}

__global__ void scan_bsum(int* __restrict__ bsum) {
    __shared__ int s[256];
    int tid = threadIdx.x;
    int v = (tid < NB_SCAN) ? bsum[tid] : 0;
    s[tid] = v;
    __syncthreads();
    #pragma unroll
    for (int off = 1; off < 256; off <<= 1) {
        int add = (tid >= off) ? s[tid - off] : 0;
        __syncthreads();
        s[tid] += add;
        __syncthreads();
    }
    if (tid < NB_SCAN) bsum[tid] = s[tid] - v;   // exclusive
}

__global__ void scan_fill(const int* __restrict__ deg, const int* __restrict__ bsum,
                          int* __restrict__ row_ptr) {
    __shared__ int s[256];
    int tid = threadIdx.x;
    int i = blockIdx.x * 256 + tid;
    int v = (i < N_NODES) ? deg[i] : 0;
    s[tid] = v;
    __syncthreads();
    #pragma unroll
    for (int off = 1; off < 256; off <<= 1) {
        int add = (tid >= off) ? s[tid - off] : 0;
        __syncthreads();
        s[tid] += add;
        __syncthreads();
    }
    int excl = s[tid] - v + bsum[blockIdx.x];
    if (i < N_NODES) row_ptr[i] = excl;
    if (i == N_NODES - 1) row_ptr[N_NODES] = excl + v;
}

// XCD-range-partitioned CSR fill, 2000 blocks, int4 loads of src+dst
__global__ void fill_csr_part(const int* __restrict__ src, const int* __restrict__ dst,
                              const int* __restrict__ row_ptr, int* __restrict__ cursor,
                              int* __restrict__ csr_src) {
    int range = blockIdx.x & (NRANGE - 1);
    int chunk = blockIdx.x >> 3;
    int lo = range * RANGE_SZ;
    int hi = lo + RANGE_SZ; if (hi > N_NODES) hi = N_NODES;
    int beg = chunk * PER_CHUNK;
    for (int e = beg + threadIdx.x * 4; e < beg + PER_CHUNK; e += 1024) {
        int4 d4 = *(const int4*)(dst + e);
        int4 s4 = *(const int4*)(src + e);
        if (d4.x >= lo && d4.x < hi) {
            int pos = atomicAdd(&cursor[d4.x], 1);
            csr_src[row_ptr[d4.x] + pos] = s4.x;
        }
        if (d4.y >= lo && d4.y < hi) {
            int pos = atomicAdd(&cursor[d4.y], 1);
            csr_src[row_ptr[d4.y] + pos] = s4.y;
        }
        if (d4.z >= lo && d4.z < hi) {
            int pos = atomicAdd(&cursor[d4.z], 1);
            csr_src[row_ptr[d4.z] + pos] = s4.z;
        }
        if (d4.w >= lo && d4.w < hi) {
            int pos = atomicAdd(&cursor[d4.w], 1);
            csr_src[row_ptr[d4.w] + pos] = s4.w;
        }
    }
}

// abuf[n][128..255] = bf16(x[n][:])  (must run BEFORE agg_x)
__global__ void cvt_x(const float* __restrict__ x, ushort* __restrict__ abuf) {
    int i = blockIdx.x * blockDim.x + threadIdx.x;
    if (i >= N_NODES * 32) return;
    int n = i >> 5, q = i & 31;
    float4 v = *(const float4*)(x + (size_t)n * 128 + q * 4);
    ushort4 o;
    o.x = f2bf(v.x); o.y = f2bf(v.y); o.z = f2bf(v.z); o.w = f2bf(v.w);
    *(ushort4*)(abuf + (size_t)n * 256 + 128 + q * 4) = o;
}

// one wave per node: mean of bf16-x[src] rows (from abuf x-half, 256B/row)
__global__ void agg_x(const int* __restrict__ row_ptr,
                      const int* __restrict__ csr_src, ushort* __restrict__ abuf) {
    int wid = threadIdx.x >> 6;
    int lane = threadIdx.x & 63;
    int n = blockIdx.x * 4 + wid;
    if (n >= N_NODES) return;
    int beg = row_ptr[n], end = row_ptr[n + 1];
    int half = lane >> 5, l32 = lane & 31;
    const ushort* xb = abuf + 128;   // x-half of each 256-elem row
    float a0 = 0, a1 = 0, a2 = 0, a3 = 0;
    float b0 = 0, b1 = 0, b2_ = 0, b3 = 0;
    int e = beg + half;
    for (; e + 2 < end; e += 4) {
        int s0 = csr_src[e], s1 = csr_src[e + 2];
        ushort4 v0 = *(const ushort4*)(xb + (size_t)s0 * 256 + l32 * 4);
        ushort4 v1 = *(const ushort4*)(xb + (size_t)s1 * 256 + l32 * 4);
        a0 += bf2f(v0.x); a1 += bf2f(v0.y); a2 += bf2f(v0.z); a3 += bf2f(v0.w);
        b0 += bf2f(v1.x); b1 += bf2f(v1.y); b2_ += bf2f(v1.z); b3 += bf2f(v1.w);
    }
    if (e < end) {
        int s = csr_src[e];
        ushort4 v = *(const ushort4*)(xb + (size_t)s * 256 + l32 * 4);
        a0 += bf2f(v.x); a1 += bf2f(v.y); a2 += bf2f(v.z); a3 += bf2f(v.w);
    }
    a0 += b0; a1 += b1; a2 += b2_; a3 += b3;
    a0 += __shfl_xor(a0, 32);
    a1 += __shfl_xor(a1, 32);
    a2 += __shfl_xor(a2, 32);
    a3 += __shfl_xor(a3, 32);
    int d = end - beg; if (d < 1) d = 1;
    float inv = 1.0f / (float)d;
    if (half == 0) {
        ushort4 o;
        o.x = f2bf(a0 * inv); o.y = f2bf(a1 * inv);
        o.z = f2bf(a2 * inv); o.w = f2bf(a3 * inv);
        *(ushort4*)(abuf + (size_t)n * 256 + l32 * 4) = o;
    }
}

// merged weight transpose+convert: wt[512][256] and wt2[80][512]
__global__ void cvt_weights(const float* __restrict__ w1l, const float* __restrict__ w1r,
                            const float* __restrict__ w2l, const float* __restrict__ w2r,
                            ushort* __restrict__ wt, ushort* __restrict__ wt2) {
    int i = blockIdx.x * blockDim.x + threadIdx.x;
    if (i < 512 * 256) {
        int k = i >> 9, c = i & 511;
        float v = (k < 128) ? w1l[(size_t)k * 512 + c] : w1r[(size_t)(k - 128) * 512 + c];
        wt[(size_t)c * 256 + k] = f2bf(v);
    } else if (i < 512 * 256 + 80 * 512) {
        int j = i - 512 * 256;
        int c = j >> 9, k = j & 511;
        float v = (c < 40) ? w2l[(size_t)k * 40 + c] : w2r[(size_t)k * 40 + (c - 40)];
        wt2[(size_t)c * 512 + k] = f2bf(v);
    }
}

// h = relu(A @ WT^T + b)  A:[50000][256] bf16, WT:[512][256] bf16 -> h bf16
// single-buffer staging + XCD swizzle + LDS-staged COALESCED epilogue (dwordx4)
#define EPI_LD 136   // epilogue LDS row stride in ushorts (272B -> 4-bank skew/row)
__global__ __launch_bounds__(256) void gemm1_mfma(
    const ushort* __restrict__ A, const ushort* __restrict__ BT,
    const float* __restrict__ bias, ushort* __restrict__ h) {
    __shared__ ushort pool[128 * EPI_LD];   // 34816B; aliases staging (32KB) + epilogue
    ushort* As = pool;            // 8192 ushorts
    ushort* Bs = pool + 8192;     // 8192 ushorts
    int tid = threadIdx.x;
    int wave = tid >> 6, lane = tid & 63;
    int wm = wave >> 1, wn = wave & 1;
    // bijective XCD swizzle (m204): nwg=1564, q=195, r=4; y-fastest mapping
    int nwg = gridDim.x;
    int q = nwg >> 3, r = nwg & 7;
    int xcd = blockIdx.x & 7, pos = blockIdx.x >> 3;
    int base = (xcd < r) ? xcd * (q + 1) : r * (q + 1) + (xcd - r) * q;
    int id = base + pos;
    int row0 = (id >> 2) * 128;
    int col0 = (id & 3) * 128;

    f32x4 acc[4][4] = {};
    for (int kk = 0; kk < 256; kk += 64) {
        #pragma unroll
        for (int c = 0; c < 4; ++c) {
            int ch = wave + c * 4;
            int o = ch * 1024 + lane * 16;
            int row = o >> 7;
            int s = (o >> 4) & 7;
            int ssrc = s ^ (row & 7);
            int gr = row0 + row; if (gr > N_NODES - 1) gr = N_NODES - 1;
            gload_lds16(A + (size_t)gr * 256 + kk + (ssrc << 3), As + ch * 512);
            int gc = col0 + row;
            gload_lds16(BT + (size_t)gc * 256 + kk + (ssrc << 3), Bs + ch * 512);
        }
        __syncthreads();
        #pragma unroll
        for (int kc = 0; kc < 2; ++kc) {
            int sbase = kc * 4 + (lane >> 4);
            bf16x8 af[4], bfr[4];
            #pragma unroll
            for (int m = 0; m < 4; ++m) {
                int row = wm * 64 + m * 16 + (lane & 15);
                af[m] = *(const bf16x8*)(As + row * 64 + ((sbase ^ (row & 7)) << 3));
            }
            #pragma unroll
            for (int n = 0; n < 4; ++n) {
                int row = wn * 64 + n * 16 + (lane & 15);
                bfr[n] = *(const bf16x8*)(Bs + row * 64 + ((sbase ^ (row & 7)) << 3));
            }
            #pragma unroll
            for (int m = 0; m < 4; ++m)
                #pragma unroll
                for (int n = 0; n < 4; ++n)
                    acc[m][n] = __builtin_amdgcn_mfma_f32_16x16x32_bf16(af[m], bfr[n], acc[m][n], 0, 0, 0);
        }
        __syncthreads();
    }

    // epilogue: bias+relu -> bf16 into padded LDS tile, then coalesced dwordx4
    #pragma unroll
    for (int n = 0; n < 4; ++n) {
        int col_l = wn * 64 + n * 16 + (lane & 15);
        float b = bias[col0 + col_l];
        #pragma unroll
        for (int m = 0; m < 4; ++m) {
            #pragma unroll
            for (int j = 0; j < 4; ++j) {
                int row_l = wm * 64 + m * 16 + (lane >> 4) * 4 + j;
                pool[row_l * EPI_LD + col_l] = f2bf(fmaxf(acc[m][n][j] + b, 0.f));
            }
        }
    }
    __syncthreads();
    #pragma unroll
    for (int it = 0; it < 8; ++it) {
        int idx = tid + it * 256;
        int row = idx >> 4, ch = idx & 15;
        int grow = row0 + row;
        if (grow < N_NODES) {
            int4 v = *(const int4*)(pool + row * EPI_LD + ch * 8);
            *(int4*)(h + (size_t)grow * 512 + col0 + ch * 8) = v;
        }
    }
}

// [p|r] = h @ wt2^T   h:[50000][512] bf16, wt2:[80][512] bf16 — 2-phase dbuf
__global__ __launch_bounds__(256) void gemm2_mfma(
    const ushort* __restrict__ hbf, const ushort* __restrict__ wt2,
    ushort* __restrict__ p, float* __restrict__ r) {
    __shared__ ushort As[2][128 * 64];
    __shared__ ushort Bs[2][80 * 64];
    int tid = threadIdx.x;
    int wave = tid >> 6, lane = tid & 63;
    int row0 = blockIdx.x * 128;
    f32x4 acc[2][5] = {};

    auto stage = [&](int buf, int kk) {
        #pragma unroll
        for (int c = 0; c < 4; ++c) {
            int ch = wave + c * 4;
            int o = ch * 1024 + lane * 16;
            int row = o >> 7;
            int s = (o >> 4) & 7;
            int ssrc = s ^ (row & 7);
            int gr = row0 + row; if (gr > N_NODES - 1) gr = N_NODES - 1;
            gload_lds16(hbf + (size_t)gr * 512 + kk + (ssrc << 3), As[buf] + ch * 512);
        }
        for (int ch = wave; ch < 10; ch += 4) {
            int o = ch * 1024 + lane * 16;
            int row = o >> 7;
            int s = (o >> 4) & 7;
            int ssrc = s ^ (row & 7);
            gload_lds16(wt2 + (size_t)row * 512 + kk + (ssrc << 3), Bs[buf] + ch * 512);
        }
    };

    stage(0, 0);
    __syncthreads();
    #pragma unroll
    for (int t = 0; t < 8; ++t) {
        int cur = t & 1;
        if (t < 7) stage(cur ^ 1, (t + 1) * 64);
        #pragma unroll
        for (int kc = 0; kc < 2; ++kc) {
            int sbase = kc * 4 + (lane >> 4);
            bf16x8 af[2], bfr[5];
            #pragma unroll
            for (int m = 0; m < 2; ++m) {
                int row = wave * 32 + m * 16 + (lane & 15);
                af[m] = *(const bf16x8*)(As[cur] + row * 64 + ((sbase ^ (row & 7)) << 3));
            }
            #pragma unroll
            for (int n = 0; n < 5; ++n) {
                int row = n * 16 + (lane & 15);
                bfr[n] = *(const bf16x8*)(Bs[cur] + row * 64 + ((sbase ^ (row & 7)) << 3));
            }
            #pragma unroll
            for (int m = 0; m < 2; ++m)
                #pragma unroll
                for (int n = 0; n < 5; ++n)
                    acc[m][n] = __builtin_amdgcn_mfma_f32_16x16x32_bf16(af[m], bfr[n], acc[m][n], 0, 0, 0);
        }
        __syncthreads();
    }
    #pragma unroll
    for (int m = 0; m < 2; ++m) {
        #pragma unroll
        for (int j = 0; j < 4; ++j) {
            int grow = row0 + wave * 32 + m * 16 + (lane >> 4) * 4 + j;
            if (grow >= N_NODES) continue;
            #pragma unroll
            for (int n = 0; n < 5; ++n) {
                int col = n * 16 + (lane & 15);
                float v = acc[m][n][j];
                if (col < 40) p[(size_t)grow * 40 + col] = f2bf(v);
                else          r[(size_t)grow * 40 + (col - 40)] = v;
            }
        }
    }
}

// out = log_softmax(mean_j p[src] + b2 + r)  one wave per node, lanes 0..39
__global__ void final_kernel(const ushort* __restrict__ p, const float* __restrict__ rr,
                             const float* __restrict__ b2,
                             const int* __restrict__ row_ptr, const int* __restrict__ csr_src,
                             float* __restrict__ out) {
    int wid = threadIdx.x >> 6;
    int lane = threadIdx.x & 63;
    int n = blockIdx.x * 4 + wid;
    if (n >= N_NODES) return;
    int beg = row_ptr[n], end = row_ptr[n + 1];
    float acc0 = 0.f, acc1 = 0.f, acc2 = 0.f, acc3 = 0.f;
    int e = beg;
    if (lane < OUT_DIM) {
        for (; e + 3 < end; e += 4) {
            int s0 = csr_src[e], s1 = csr_src[e + 1];
            int s2 = csr_src[e + 2], s3 = csr_src[e + 3];
            acc0 += bf2f(p[(size_t)s0 * OUT_DIM + lane]);
            acc1 += bf2f(p[(size_t)s1 * OUT_DIM + lane]);
            acc2 += bf2f(p[(size_t)s2 * OUT_DIM + lane]);
            acc3 += bf2f(p[(size_t)s3 * OUT_DIM + lane]);
        }
        for (; e < end; ++e)
            acc0 += bf2f(p[(size_t)csr_src[e] * OUT_DIM + lane]);
    }
    int d = end - beg; if (d < 1) d = 1;
    float inv = 1.0f / (float)d;
    float v = (lane < OUT_DIM)
                  ? ((acc0 + acc1 + acc2 + acc3) * inv + b2[lane] + rr[(size_t)n * OUT_DIM + lane])
                  : -INFINITY;
    float m = v;
    #pragma unroll
    for (int off = 32; off; off >>= 1) m = fmaxf(m, __shfl_xor(m, off));
    float ex = (lane < OUT_DIM) ? expf(v - m) : 0.f;
    float ssum = ex;
    #pragma unroll
    for (int off = 32; off; off >>= 1) ssum += __shfl_xor(ssum, off);
    if (lane < OUT_DIM) out[(size_t)n * OUT_DIM + lane] = (v - m) - logf(ssum);
}

extern "C" void kernel_launch(void* const* d_in, const int* in_sizes, int n_in,
                              void* d_out, int out_size, void* d_ws, size_t ws_size,
                              hipStream_t stream) {
    const float* x    = (const float*)d_in[0];
    const int*   edge = (const int*)d_in[1];
    const int*   srce = edge;
    const int*   dste = edge + N_EDGES;
    const float* w1l  = (const float*)d_in[2];
    const float* b1   = (const float*)d_in[3];
    const float* w1r  = (const float*)d_in[4];
    const float* w2l  = (const float*)d_in[5];
    const float* b2   = (const float*)d_in[6];
    const float* w2r  = (const float*)d_in[7];
    float* out = (float*)d_out;

    char* ws = (char*)d_ws;
    size_t off = 0;
    auto alloc = [&](size_t bytes) -> void* {
        void* ptr = ws + off;
        off = (off + bytes + 255) & ~(size_t)255;
        return ptr;
    };
    int* deg     = (int*)alloc((size_t)2 * N_NODES * 4);
    int* cursor  = deg + N_NODES;
    int* row_ptr = (int*)alloc((size_t)(N_NODES + 1) * 4);
    int* bsum    = (int*)alloc((size_t)NB_SCAN * 4);
    int* csr_src = (int*)alloc((size_t)N_EDGES * 4);
    ushort* abuf = (ushort*)alloc((size_t)N_NODES * 256 * 2);   // [agg|x] bf16
    ushort* wt   = (ushort*)alloc((size_t)512 * 256 * 2);       // [w1_l;w1_r]^T bf16
    ushort* wt2  = (ushort*)alloc((size_t)80 * 512 * 2);        // [w2_l|w2_r]^T bf16
    ushort* h    = (ushort*)alloc((size_t)N_NODES * HID * 2);   // h bf16
    ushort* p    = (ushort*)alloc((size_t)N_NODES * OUT_DIM * 2);  // p bf16
    float* rbuf  = (float*)alloc((size_t)N_NODES * OUT_DIM * 4);

    zero_ints<<<(2 * N_NODES + 255) / 256, 256, 0, stream>>>(deg, 2 * N_NODES);
    count_deg_part<<<NRANGE * NCHUNK, 256, 0, stream>>>(dste, deg);
    deg_block_sums<<<NB_SCAN, 256, 0, stream>>>(deg, bsum);
    scan_bsum<<<1, 256, 0, stream>>>(bsum);
    scan_fill<<<NB_SCAN, 256, 0, stream>>>(deg, bsum, row_ptr);
    fill_csr_part<<<NRANGE * NCHUNK, 256, 0, stream>>>(srce, dste, row_ptr, cursor, csr_src);
    cvt_x<<<(N_NODES * 32 + 255) / 256, 256, 0, stream>>>(x, abuf);
    cvt_weights<<<(512 * 256 + 80 * 512 + 255) / 256, 256, 0, stream>>>(w1l, w1r, w2l, w2r, wt, wt2);
    agg_x<<<(N_NODES + 3) / 4, 256, 0, stream>>>(row_ptr, csr_src, abuf);
    gemm1_mfma<<<4 * ((N_NODES + 127) / 128), 256, 0, stream>>>(abuf, wt, b1, h);
    gemm2_mfma<<<(N_NODES + 127) / 128, 256, 0, stream>>>(h, wt2, p, rbuf);
    final_kernel<<<(N_NODES + 3) / 4, 256, 0, stream>>>(p, rbuf, b2, row_ptr, csr_src, out);
}